// Round 1
// baseline (1813.922 us; speedup 1.0000x reference)
//
#include <hip/hip_runtime.h>
#include <math.h>

#define D_MODEL   1024
#define D_INNER   2048
#define HEADDIM   64
#define NHEADS    32
#define D_STATE   128
#define D_CONV    4
#define CONV_DIM  2304      // D_INNER + 2*D_STATE
#define D_IN_PROJ 4384      // 2*D_INNER + 2*D_STATE + NHEADS
#define LSEQ      2048
#define BATCH     2
#define NROWS     4096      // BATCH * LSEQ

// ---------------------------------------------------------------------------
// GEMM:  C[m][n] = sum_k A[m*K + k] * B[n*K + k]    (both K-major, "NT")
// 128x128 tile, BK=16, 8x8 micro-tile, 256 threads.
// ---------------------------------------------------------------------------
#define BM 128
#define BN 128
#define BK 16
#define LDP 132   // padded row length (+4) to kill LDS write conflicts

__global__ __launch_bounds__(256) void gemm_nt(
    const float* __restrict__ A, const float* __restrict__ B,
    float* __restrict__ C, int M, int N, int K) {
  __shared__ __align__(16) float sA[BK][LDP];
  __shared__ __align__(16) float sB[BK][LDP];
  const int tid = threadIdx.x;
  const int row0 = blockIdx.y * BM;
  const int col0 = blockIdx.x * BN;
  const int tx = tid & 15;   // 0..15 -> columns
  const int ty = tid >> 4;   // 0..15 -> rows

  float acc[8][8] = {};

  for (int k0 = 0; k0 < K; k0 += BK) {
    // ---- stage A tile (BM x BK) and B tile (BN x BK), float4 along K ----
    #pragma unroll
    for (int i = 0; i < 2; ++i) {
      int f  = tid + i * 256;      // 0..511 float4 slots
      int m  = f >> 2;             // 0..127
      int kq = f & 3;              // float4 slot in K
      // A
      {
        int gm = row0 + m;
        float4 v = make_float4(0.f, 0.f, 0.f, 0.f);
        if (gm < M)
          v = *reinterpret_cast<const float4*>(&A[(size_t)gm * K + k0 + kq * 4]);
        sA[kq * 4 + 0][m] = v.x; sA[kq * 4 + 1][m] = v.y;
        sA[kq * 4 + 2][m] = v.z; sA[kq * 4 + 3][m] = v.w;
      }
      // B
      {
        int gn = col0 + m;
        float4 v = make_float4(0.f, 0.f, 0.f, 0.f);
        if (gn < N)
          v = *reinterpret_cast<const float4*>(&B[(size_t)gn * K + k0 + kq * 4]);
        sB[kq * 4 + 0][m] = v.x; sB[kq * 4 + 1][m] = v.y;
        sB[kq * 4 + 2][m] = v.z; sB[kq * 4 + 3][m] = v.w;
      }
    }
    __syncthreads();

    #pragma unroll
    for (int kk = 0; kk < BK; ++kk) {
      float4 a0 = *reinterpret_cast<const float4*>(&sA[kk][ty * 8]);
      float4 a1 = *reinterpret_cast<const float4*>(&sA[kk][ty * 8 + 4]);
      float4 b0 = *reinterpret_cast<const float4*>(&sB[kk][tx * 4]);
      float4 b1 = *reinterpret_cast<const float4*>(&sB[kk][64 + tx * 4]);
      float a[8] = {a0.x, a0.y, a0.z, a0.w, a1.x, a1.y, a1.z, a1.w};
      float b[8] = {b0.x, b0.y, b0.z, b0.w, b1.x, b1.y, b1.z, b1.w};
      #pragma unroll
      for (int i = 0; i < 8; ++i)
        #pragma unroll
        for (int j = 0; j < 8; ++j)
          acc[i][j] = fmaf(a[i], b[j], acc[i][j]);
    }
    __syncthreads();
  }

  // ---- store: columns are split tx*4.. and 64+tx*4.. ----
  #pragma unroll
  for (int i = 0; i < 8; ++i) {
    int gm = row0 + ty * 8 + i;
    if (gm >= M) continue;
    #pragma unroll
    for (int j = 0; j < 8; ++j) {
      int cn = (j < 4) ? (tx * 4 + j) : (64 + tx * 4 + (j - 4));
      int gn = col0 + cn;
      if (gn < N) C[(size_t)gm * N + gn] = acc[i][j];
    }
  }
}

// ---------------------------------------------------------------------------
// depthwise causal conv (K=4) + bias + silu.  reads xBC slice of zxbcdt.
// grid (CONV_DIM/256, L, B)
// ---------------------------------------------------------------------------
__global__ __launch_bounds__(256) void conv_silu_kernel(
    const float* __restrict__ zxbcdt, const float* __restrict__ conv_w,
    const float* __restrict__ conv_b, float* __restrict__ xconv) {
  const int c = blockIdx.x * 256 + threadIdx.x;   // 0..2303
  const int l = blockIdx.y;
  const int b = blockIdx.z;
  const float* src = zxbcdt + ((size_t)b * LSEQ) * D_IN_PROJ + D_INNER + c;
  float w0 = conv_w[c * 4 + 0], w1 = conv_w[c * 4 + 1];
  float w2 = conv_w[c * 4 + 2], w3 = conv_w[c * 4 + 3];
  float acc = conv_b[c];
  if (l >= 3) acc = fmaf(w0, src[(size_t)(l - 3) * D_IN_PROJ], acc);
  if (l >= 2) acc = fmaf(w1, src[(size_t)(l - 2) * D_IN_PROJ], acc);
  if (l >= 1) acc = fmaf(w2, src[(size_t)(l - 1) * D_IN_PROJ], acc);
  acc = fmaf(w3, src[(size_t)l * D_IN_PROJ], acc);
  float s = acc / (1.f + expf(-acc));     // silu
  xconv[((size_t)b * LSEQ + l) * CONV_DIM + c] = s;
}

// ---------------------------------------------------------------------------
// dt = softplus(dt_raw + dt_bias); dA = exp(dt * (-exp(A_log)))
// ---------------------------------------------------------------------------
__global__ __launch_bounds__(256) void dt_kernel(
    const float* __restrict__ zxbcdt, const float* __restrict__ dt_bias,
    const float* __restrict__ A_log, float* __restrict__ dt_out,
    float* __restrict__ dA_out) {
  int idx = blockIdx.x * 256 + threadIdx.x;       // NROWS*NHEADS
  int h = idx & 31;
  int row = idx >> 5;
  float x = zxbcdt[(size_t)row * D_IN_PROJ + (D_INNER + CONV_DIM) + h] + dt_bias[h];
  float dt = (x > 20.f) ? x : log1pf(expf(x));
  float A = -expf(A_log[h]);
  dt_out[idx] = dt;
  dA_out[idx] = expf(dt * A);
}

// ---------------------------------------------------------------------------
// SSD sequential scan.  one WG per (b,h); 512 threads.
// thread: p = tid>>3 (0..63), g = tid&7.  owns n in float4-chunks {g,8+g,16+g,24+g}
// h_state: 16 regs.  y reduced over the 8-lane g-group via shfl_xor.
// ---------------------------------------------------------------------------
__global__ __launch_bounds__(512) void scan_kernel(
    const float* __restrict__ xconv, const float* __restrict__ dt_arr,
    const float* __restrict__ dA_arr, float* __restrict__ y) {
  const int b = blockIdx.x >> 5;
  const int h = blockIdx.x & 31;
  const int tid = threadIdx.x;
  const int p = tid >> 3;
  const int g = tid & 7;

  __shared__ __align__(16) float sB[16][D_STATE];
  __shared__ __align__(16) float sC[16][D_STATE];
  __shared__ __align__(16) float sx[16][HEADDIM];
  __shared__ float sdA[16], sdt[16];

  float hst[16] = {};

  for (int t0 = 0; t0 < LSEQ; t0 += 16) {
    __syncthreads();
    for (int idx = tid; idx < 16 * D_STATE; idx += 512) {
      int t = idx >> 7, n = idx & 127;
      size_t base = ((size_t)(b * LSEQ + t0 + t)) * CONV_DIM;
      sB[t][n] = xconv[base + D_INNER + n];
      sC[t][n] = xconv[base + D_INNER + D_STATE + n];
    }
    for (int idx = tid; idx < 16 * HEADDIM; idx += 512) {
      int t = idx >> 6, pp = idx & 63;
      sx[t][pp] = xconv[((size_t)(b * LSEQ + t0 + t)) * CONV_DIM + h * HEADDIM + pp];
    }
    if (tid < 16) {
      int row = b * LSEQ + t0 + tid;
      sdA[tid] = dA_arr[(size_t)row * NHEADS + h];
      sdt[tid] = dt_arr[(size_t)row * NHEADS + h];
    }
    __syncthreads();

    for (int tc = 0; tc < 16; ++tc) {
      float dA  = sdA[tc];
      float xv  = sx[tc][p];
      float dtx = sdt[tc] * xv;
      float yacc = 0.f;
      #pragma unroll
      for (int jj = 0; jj < 4; ++jj) {
        float4 bv = *reinterpret_cast<const float4*>(&sB[tc][(jj * 8 + g) * 4]);
        float4 cv = *reinterpret_cast<const float4*>(&sC[tc][(jj * 8 + g) * 4]);
        float* hs = &hst[jj * 4];
        hs[0] = fmaf(dA, hs[0], dtx * bv.x); yacc = fmaf(hs[0], cv.x, yacc);
        hs[1] = fmaf(dA, hs[1], dtx * bv.y); yacc = fmaf(hs[1], cv.y, yacc);
        hs[2] = fmaf(dA, hs[2], dtx * bv.z); yacc = fmaf(hs[2], cv.z, yacc);
        hs[3] = fmaf(dA, hs[3], dtx * bv.w); yacc = fmaf(hs[3], cv.w, yacc);
      }
      yacc += __shfl_xor(yacc, 1);
      yacc += __shfl_xor(yacc, 2);
      yacc += __shfl_xor(yacc, 4);
      if (g == 0)
        y[((size_t)(b * LSEQ + t0 + tc)) * D_INNER + h * HEADDIM + p] = yacc;
    }
  }
}

// ---------------------------------------------------------------------------
// y = (y_scan + D_skip*xh) * silu(z);  y *= rsqrt(mean(y^2)+eps)*norm_w
// one WG (256) per row; 8 elems/thread.  in-place on y.
// ---------------------------------------------------------------------------
__global__ __launch_bounds__(256) void gate_rms_kernel(
    float* __restrict__ y, const float* __restrict__ zxbcdt,
    const float* __restrict__ xconv, const float* __restrict__ D_skip,
    const float* __restrict__ norm_w) {
  const int row = blockIdx.x;
  const int tid = threadIdx.x;
  float v[8];
  float acc = 0.f;
  #pragma unroll
  for (int i = 0; i < 8; ++i) {
    int d = i * 256 + tid;
    float ys = y[(size_t)row * D_INNER + d];
    float xh = xconv[(size_t)row * CONV_DIM + d];
    float Dh = D_skip[d >> 6];
    float z  = zxbcdt[(size_t)row * D_IN_PROJ + d];
    float gz = z / (1.f + expf(-z));
    float val = fmaf(Dh, xh, ys) * gz;
    v[i] = val;
    acc = fmaf(val, val, acc);
  }
  #pragma unroll
  for (int off = 32; off; off >>= 1) acc += __shfl_xor(acc, off);
  __shared__ float wsum[4];
  if ((tid & 63) == 0) wsum[tid >> 6] = acc;
  __syncthreads();
  float total = wsum[0] + wsum[1] + wsum[2] + wsum[3];
  float scale = rsqrtf(total / (float)D_INNER + 1e-5f);
  #pragma unroll
  for (int i = 0; i < 8; ++i) {
    int d = i * 256 + tid;
    y[(size_t)row * D_INNER + d] = v[i] * scale * norm_w[d];
  }
}

// ---------------------------------------------------------------------------
// LayerNorm(out_pre) * ln_g + ln_b + residual(x)
// ---------------------------------------------------------------------------
__global__ __launch_bounds__(256) void ln_kernel(
    const float* __restrict__ o, const float* __restrict__ x,
    const float* __restrict__ lng, const float* __restrict__ lnb,
    float* __restrict__ out) {
  const int row = blockIdx.x;
  const int tid = threadIdx.x;
  float v[4];
  float s = 0.f, s2 = 0.f;
  #pragma unroll
  for (int i = 0; i < 4; ++i) {
    int d = i * 256 + tid;
    float t = o[(size_t)row * D_MODEL + d];
    v[i] = t;
    s += t;
    s2 = fmaf(t, t, s2);
  }
  #pragma unroll
  for (int off = 32; off; off >>= 1) {
    s  += __shfl_xor(s, off);
    s2 += __shfl_xor(s2, off);
  }
  __shared__ float sa[4], sb[4];
  if ((tid & 63) == 0) { sa[tid >> 6] = s; sb[tid >> 6] = s2; }
  __syncthreads();
  s  = sa[0] + sa[1] + sa[2] + sa[3];
  s2 = sb[0] + sb[1] + sb[2] + sb[3];
  float mu  = s / (float)D_MODEL;
  float var = s2 / (float)D_MODEL - mu * mu;
  float inv = rsqrtf(var + 1e-5f);
  #pragma unroll
  for (int i = 0; i < 4; ++i) {
    int d = i * 256 + tid;
    out[(size_t)row * D_MODEL + d] =
        (v[i] - mu) * inv * lng[d] + lnb[d] + x[(size_t)row * D_MODEL + d];
  }
}

// ---------------------------------------------------------------------------
extern "C" void kernel_launch(void* const* d_in, const int* in_sizes, int n_in,
                              void* d_out, int out_size, void* d_ws, size_t ws_size,
                              hipStream_t stream) {
  const float* x         = (const float*)d_in[0];
  const float* in_proj_w = (const float*)d_in[1];
  const float* conv_w    = (const float*)d_in[2];
  const float* conv_b    = (const float*)d_in[3];
  const float* dt_bias   = (const float*)d_in[4];
  const float* A_log     = (const float*)d_in[5];
  const float* D_skip    = (const float*)d_in[6];
  const float* norm_w    = (const float*)d_in[7];
  const float* out_w     = (const float*)d_in[8];
  const float* ln_g      = (const float*)d_in[9];
  const float* ln_b      = (const float*)d_in[10];
  float* out = (float*)d_out;

  float* ws      = (float*)d_ws;
  float* zxbcdt  = ws;                                    // NROWS * D_IN_PROJ
  float* xconv   = zxbcdt + (size_t)NROWS * D_IN_PROJ;    // NROWS * CONV_DIM
  float* dt_s    = xconv + (size_t)NROWS * CONV_DIM;      // NROWS * NHEADS
  float* dA_s    = dt_s + (size_t)NROWS * NHEADS;
  float* ybuf    = dA_s + (size_t)NROWS * NHEADS;         // NROWS * D_INNER
  float* outpre  = zxbcdt;   // reuse: zxbcdt dead after gate_rms

  // 1. in_proj GEMM: (4096 x 1024) @ (4384 x 1024)^T
  gemm_nt<<<dim3((D_IN_PROJ + BN - 1) / BN, NROWS / BM), dim3(256), 0, stream>>>(
      x, in_proj_w, zxbcdt, NROWS, D_IN_PROJ, D_MODEL);

  // 2. conv + silu
  conv_silu_kernel<<<dim3(CONV_DIM / 256, LSEQ, BATCH), dim3(256), 0, stream>>>(
      zxbcdt, conv_w, conv_b, xconv);

  // 3. dt / dA
  dt_kernel<<<dim3(NROWS * NHEADS / 256), dim3(256), 0, stream>>>(
      zxbcdt, dt_bias, A_log, dt_s, dA_s);

  // 4. scan
  scan_kernel<<<dim3(BATCH * NHEADS), dim3(512), 0, stream>>>(
      xconv, dt_s, dA_s, ybuf);

  // 5. gate + rmsnorm (in place on ybuf)
  gate_rms_kernel<<<dim3(NROWS), dim3(256), 0, stream>>>(
      ybuf, zxbcdt, xconv, D_skip, norm_w);

  // 6. out_proj GEMM: (4096 x 2048) @ (1024 x 2048)^T
  gemm_nt<<<dim3(D_MODEL / BN, NROWS / BM), dim3(256), 0, stream>>>(
      ybuf, out_w, outpre, NROWS, D_MODEL, D_INNER);

  // 7. layernorm + residual
  ln_kernel<<<dim3(NROWS), dim3(256), 0, stream>>>(
      outpre, x, ln_g, ln_b, out);
}